// Round 16
// baseline (401.307 us; speedup 1.0000x reference)
//
#include <hip/hip_runtime.h>
#include <hip/hip_fp16.h>
#include <math.h>

// Problem constants
#define NN   20000     // nodes
#define NE   320000    // edges
#define NIN  128       // node input dim
#define HC   256       // heads(4) * hidden(64)
#define NB   1024      // fused GEMM output width: [q | kv-interleaved | qproj]

typedef unsigned short u16;
typedef __attribute__((ext_vector_type(8))) short bf16x8;
typedef __attribute__((ext_vector_type(8))) unsigned short u16x8;
typedef __attribute__((ext_vector_type(4))) float f32x4;

__device__ __forceinline__ float bf2f(u16 u) {
  union { unsigned int i; float f; } x;
  x.i = ((unsigned int)u) << 16;
  return x.f;
}
__device__ __forceinline__ u16 f2bf(float f) {
  union { float f; unsigned int i; } x;
  x.f = f;
  unsigned int r = x.i + 0x7fffu + ((x.i >> 16) & 1u);
  return (u16)(r >> 16);
}

// dtype-flexible loads (flags detected on device each launch)
__device__ __forceinline__ float ldf(const void* p, int i, bool fbf) {
  return fbf ? bf2f(((const u16*)p)[i]) : ((const float*)p)[i];
}
__device__ __forceinline__ int ldsrc(const void* p, int e, bool is64) {
  const int* p32 = (const int*)p;
  return is64 ? p32[2 * e] : p32[e];
}
__device__ __forceinline__ int lddst(const void* p, int e, bool is64) {
  const int* p32 = (const int*)p;
  return is64 ? p32[2 * (NE + e)] : p32[NE + e];
}
__device__ __forceinline__ void stout(void* p, int i, float v, bool fbf) {
  if (fbf) ((u16*)p)[i] = f2bf(v);
  else ((float*)p)[i] = v;
}

// async global->LDS, 16B per lane
__device__ __forceinline__ void gload_lds16(const u16* g, u16* l) {
  __builtin_amdgcn_global_load_lds(
      (const __attribute__((address_space(1))) void*)g,
      (__attribute__((address_space(3))) void*)l, 16, 0, 0);
}

// ---------------- detection + div_term init ----------------
__global__ void devinit_kernel(const void* __restrict__ eidx,
                               const void* __restrict__ nemb,
                               int* __restrict__ flags, float* __restrict__ divt) {
  int lane = threadIdx.x;
  if (lane < 32) {
    const float c32 = (float)(-0.14391156831212787);
    float prod = (float)(2 * lane) * c32;
    divt[lane] = (float)exp((double)prod);
  }
  if (lane == 0) {
    const int* p32 = (const int*)eidx;
    int is64 = 1;
    for (int i = 1; i < 128; i += 2)
      if (p32[i] != 0) { is64 = 0; break; }
    const u16* q16 = (const u16*)nemb;
    int fbf = 1;
    for (int i = 0; i < 128; i += 2) {
      unsigned e = (q16[i] >> 7) & 0xFF;
      if (e < 90 || e > 140) { fbf = 0; break; }
    }
    flags[0] = is64;
    flags[1] = fbf;
  }
}

__global__ void sentinel_kernel(const int* __restrict__ flags, void* __restrict__ out) {
  int i = blockIdx.x * 256 + threadIdx.x;
  if (i < NE) stout(out, i, 3000.0f, flags[1] != 0);
}
__global__ void raw_sentinel_kernel(u16* __restrict__ out) {
  int i = blockIdx.x * 256 + threadIdx.x;
  if (i < NE) out[i] = f2bf(3000.0f);
}

// ---------------- CSR build ----------------
__global__ void zero_kernel(int* __restrict__ p, int n) {
  int i = blockIdx.x * 256 + threadIdx.x;
  if (i < n) p[i] = 0;
}

__global__ void hist_kernel(const int* __restrict__ flags, const void* __restrict__ eidx,
                            int* __restrict__ cnt) {
  bool is64 = flags[0] != 0;
  int e = blockIdx.x * 256 + threadIdx.x;
  if (e < NE) {
    int d = lddst(eidx, e, is64);
    if ((unsigned)d < NN) atomicAdd(&cnt[d], 1);
  }
}

__global__ void scan1_kernel(const int* __restrict__ cnt, int* __restrict__ offs,
                             int* __restrict__ bsum, int n) {
  __shared__ int s[256];
  int b = blockIdx.x, t = threadIdx.x, i = b * 256 + t;
  int x = (i < n) ? cnt[i] : 0;
  s[t] = x;
  __syncthreads();
  for (int off = 1; off < 256; off <<= 1) {
    int y = (t >= off) ? s[t - off] : 0;
    __syncthreads();
    s[t] += y;
    __syncthreads();
  }
  if (i < n) offs[i] = s[t] - x;
  if (t == 255) bsum[b] = s[t];
}

__global__ void scan2_kernel(int* __restrict__ bsum, int* __restrict__ offs,
                             int nb, int n) {
  __shared__ int s[256];
  int t = threadIdx.x;
  int x = (t < nb) ? bsum[t] : 0;
  s[t] = x;
  __syncthreads();
  for (int off = 1; off < 256; off <<= 1) {
    int y = (t >= off) ? s[t - off] : 0;
    __syncthreads();
    s[t] += y;
    __syncthreads();
  }
  if (t < nb) bsum[t] = s[t] - x;
  if (t == 255) offs[n] = s[t];
}

__global__ void scan3_kernel(int* __restrict__ offs, const int* __restrict__ bsum,
                             int* __restrict__ cursor, int n) {
  int i = blockIdx.x * 256 + threadIdx.x;
  if (i < n) {
    int v = offs[i] + bsum[blockIdx.x];
    offs[i] = v;
    cursor[i] = v;
  }
}

__global__ void fill_kernel(const int* __restrict__ flags, const void* __restrict__ eidx,
                            const void* __restrict__ rawt, const void* __restrict__ noise,
                            int* __restrict__ cursor, int* __restrict__ ssrc,
                            float* __restrict__ stt) {
  bool is64 = flags[0] != 0, fbf = flags[1] != 0;
  int e = blockIdx.x * 256 + threadIdx.x;
  if (e < NE) {
    int d = lddst(eidx, e, is64);
    if ((unsigned)d < NN) {
      int pos = atomicAdd(&cursor[d], 1);
      if ((unsigned)pos < NE) {
        int src = ldsrc(eidx, e, is64);
        if ((unsigned)src >= NN) src = 0;
        ssrc[pos] = src;
        stt[pos] = ldf(rawt, e, fbf) + ldf(noise, e, fbf);
      }
    }
  }
}

// ---------------- te_s[p][64] (f16) — double range reduction + fast sincos --------
__global__ __launch_bounds__(256) void te_kernel(
    const float* __restrict__ stt, const float* __restrict__ divt,
    u16* __restrict__ te_s) {
  int idx = blockIdx.x * 256 + threadIdx.x;
  int p = idx >> 5;          // 32 freqs per edge
  if (p >= NE) return;
  int f = idx & 31;
  float tt = stt[p];
  float arg = tt * divt[f];
  // reduce the fp32 arg mod 2π in double (error ~1e-11 rad << f16 rounding)
  double rev = (double)arg * 0.15915494309189535;   // /(2π)
  double fr = rev - floor(rev);                     // [0,1)
  float red = (float)(fr * 6.283185307179586);      // [0,2π) — sincosf fast path
  float sv, cv;
  sincosf(red, &sv, &cv);
  __half hs = __float2half(sv), hc = __float2half(cv);
  unsigned int packed = (unsigned int)(*(u16*)&hs) | ((unsigned int)(*(u16*)&hc) << 16);
  ((unsigned int*)te_s)[(size_t)p * 32 + f] = packed;
}

// ---------------- merged weight transpose: 3 matrices -> WtBig rows 0/256/512 -----
__global__ void transw3_kernel(const int* __restrict__ flags, const void* __restrict__ W0,
                               const void* __restrict__ W1, const void* __restrict__ W2,
                               u16* __restrict__ WtBig, int K) {
  bool fbf = flags[1] != 0;
  __shared__ u16 tile[64][65];
  int z = blockIdx.z;
  const void* W = (z == 0) ? W0 : (z == 1) ? W1 : W2;
  u16* dst = WtBig + (size_t)z * 256 * K;
  int kb = blockIdx.x * 64, cb = blockIdx.y * 64;
  int tx = threadIdx.x & 63, ty = threadIdx.x >> 6;
  for (int i = ty; i < 64; i += 4)
    tile[tx][i] = f2bf(ldf(W, (kb + i) * HC + cb + tx, fbf));
  __syncthreads();
  for (int i = ty; i < 64; i += 4)
    dst[(size_t)(cb + i) * K + kb + tx] = tile[i][tx];
}

// ---------------- wcomb + biasBig merged ----------------
__global__ void wcombbias_kernel(const int* __restrict__ flags, const void* __restrict__ wt,
                                 const u16* __restrict__ Wqt, u16* __restrict__ Wout,
                                 const void* __restrict__ bq, const void* __restrict__ bk,
                                 const void* __restrict__ bv, float* __restrict__ biasBig,
                                 int K) {
  bool fbf = flags[1] != 0;
  int b = blockIdx.x, t = threadIdx.x;
  if (b < 256) {
    __shared__ float wrow[64];
    int j = b, h = j >> 6;
    if (t < 64) wrow[t] = ldf(wt, (j & 63) * HC + h * 64 + t, fbf);
    __syncthreads();
    if (t < K) {
      float s = 0.f;
#pragma unroll 8
      for (int mm = 0; mm < 64; ++mm)
        s += wrow[mm] * bf2f(Wqt[(size_t)(h * 64 + mm) * K + t]);
      Wout[(size_t)j * K + t] = f2bf(s);
    }
  } else if (b < 259) {
    int bb = b - 256;
    const void* p = (bb == 0) ? bq : (bb == 1) ? bk : bv;
    biasBig[bb * 256 + t] = ldf(p, t, fbf);
  } else {
    int j = t, h = j >> 6;
    float s = 0.f;
    for (int mm = 0; mm < 64; ++mm)
      s += ldf(bq, h * 64 + mm, fbf) * ldf(wt, (j & 63) * HC + h * 64 + mm, fbf);
    biasBig[768 + j] = s;
  }
}

// ---------------- fused MFMA GEMM (direct-to-LDS, swizzled, kv-interleave) --------
template <bool AWS>
__global__ __launch_bounds__(256) void gemm_mfma(
    const int* __restrict__ flags, const void* __restrict__ Ap,
    const u16* __restrict__ Wt, const float* __restrict__ bias,
    u16* __restrict__ C, int M, int K) {
  bool fbf = flags[1] != 0;
  __shared__ u16 As[64 * 32];
  __shared__ u16 Bs[64 * 32];
  int tid = threadIdx.x;
  int rb = blockIdx.x * 64, cb = blockIdx.y * 64;
  int wave = tid >> 6, lane = tid & 63;
  int l15 = lane & 15, quad = lane >> 4;

  f32x4 acc[4];
#pragma unroll
  for (int mt = 0; mt < 4; ++mt)
#pragma unroll
    for (int r = 0; r < 4; ++r) acc[mt][r] = 0.f;

  int srow = tid >> 2;
  int schunk = tid & 3;
  int gchunk = schunk ^ (srow & 3);
  int arow = rb + srow; if (arow >= M) arow = M - 1;
  u16* asl = &As[srow * 32 + schunk * 8];
  u16* bsl = &Bs[srow * 32 + schunk * 8];
  const u16* bsrc = Wt + (size_t)(cb + srow) * K + gchunk * 8;
  const bool adirect = AWS || fbf;
  const u16* asrc = adirect ? ((const u16*)Ap + (size_t)arow * K + gchunk * 8) : (const u16*)0;

  for (int kk = 0; kk < K; kk += 32) {
    if (adirect) {
      gload_lds16(asrc + kk, asl);
    } else {
      const float* A = (const float*)Ap + (size_t)arow * K + kk + gchunk * 8;
      bf16x8 tmp;
#pragma unroll
      for (int i = 0; i < 8; ++i) tmp[i] = (short)f2bf(A[i]);
      *(bf16x8*)asl = tmp;
    }
    gload_lds16(bsrc + kk, bsl);
    __syncthreads();

    int bcol = wave * 16 + l15;
    bf16x8 bfrag = *(const bf16x8*)&Bs[bcol * 32 + ((quad ^ (bcol & 3)) * 8)];
#pragma unroll
    for (int mt = 0; mt < 4; ++mt) {
      int ar = mt * 16 + l15;
      bf16x8 afrag = *(const bf16x8*)&As[ar * 32 + ((quad ^ (ar & 3)) * 8)];
      acc[mt] = __builtin_amdgcn_mfma_f32_16x16x32_bf16(afrag, bfrag, acc[mt], 0, 0, 0);
    }
    __syncthreads();
  }

  int gcol = cb + wave * 16 + l15;
  float bv = bias[gcol];
  int scol;
  if (gcol < 256) scol = gcol;
  else if (gcol < 512) { int cc = gcol - 256; scol = 256 + ((cc >> 2) << 3) + (cc & 3); }
  else if (gcol < 768) { int cc = gcol - 512; scol = 256 + ((cc >> 2) << 3) + 4 + (cc & 3); }
  else scol = gcol;
#pragma unroll
  for (int mt = 0; mt < 4; ++mt) {
#pragma unroll
    for (int r = 0; r < 4; ++r) {
      int grow = rb + mt * 16 + quad * 4 + r;
      if (grow < M) C[(size_t)grow * NB + scol] = f2bf(acc[mt][r] + bv);
    }
  }
}

// ---------------- fused alpha + ONLINE softmax + aggregation + relu ---------------
// Block = 2 nodes x 2 half-waves. Each half-wave runs the 4-unroll loop on half the
// node's edges; halves merge via LDS (rescaled online-softmax combine).
// DOY: fold edge-scorer projection y[n]=x[n].wc into the epilogue (layer 2).
template <int DOY>
__global__ __launch_bounds__(256) void aggfused_kernel(
    const int* __restrict__ flags, const int* __restrict__ ssrc,
    const int* __restrict__ offsets, const u16* __restrict__ te_s,
    const u16* __restrict__ qkvp, const void* __restrict__ bt,
    u16* __restrict__ xout, const void* __restrict__ wc,
    float* __restrict__ ynode) {
  bool fbf = flags[1] != 0;
  __shared__ float mrg[2][64][6];
  int w = threadIdx.x >> 6;
  int nslot = w >> 1, half = w & 1;
  int n = blockIdx.x * 2 + nslot;
  bool valid = (n < NN);
  int lane = threadIdx.x & 63;
  int c = lane * 4;

  float m = -INFINITY, denom = 0.f;
  float acc0 = 0.f, acc1 = 0.f, acc2 = 0.f, acc3 = 0.f;
  float qx = 0.f, qy = 0.f, qz = 0.f, qw = 0.f, qb = 0.f;

  if (valid) {
    int s0 = offsets[n], s1 = offsets[n + 1];
    if (s0 < 0) s0 = 0;
    if (s1 > NE) s1 = NE;
    int len = s1 - s0;
    int mid = s0 + ((len + 1) >> 1);
    int r0 = half ? mid : s0;
    int r1 = half ? s1 : mid;

    ushort4 q4 = *(const ushort4*)(qkvp + (size_t)n * NB + c);
    ushort4 p4 = *(const ushort4*)(qkvp + (size_t)n * NB + 768 + c);
    qx = bf2f(q4.x); qy = bf2f(q4.y); qz = bf2f(q4.z); qw = bf2f(q4.w);
    float px = bf2f(p4.x), py = bf2f(p4.y), pz = bf2f(p4.z), pw = bf2f(p4.w);
    float pb = qx * ldf(bt, c + 0, fbf);
    pb += qy * ldf(bt, c + 1, fbf);
    pb += qz * ldf(bt, c + 2, fbf);
    pb += qw * ldf(bt, c + 3, fbf);
    pb += __shfl_xor(pb, 1);
    pb += __shfl_xor(pb, 2);
    pb += __shfl_xor(pb, 4);
    pb += __shfl_xor(pb, 8);
    qb = pb;
    int jb = c & 63;
    int kvoff = 256 + lane * 8;

#define ALPHA_OF(kv, t4, out_a, okflag)                                        \
  {                                                                            \
    float s = qx * bf2f((kv)[0]) + __half2float(*(__half*)&(t4).x) * px;       \
    s += qy * bf2f((kv)[1]) + __half2float(*(__half*)&(t4).y) * py;            \
    s += qz * bf2f((kv)[2]) + __half2float(*(__half*)&(t4).z) * pz;            \
    s += qw * bf2f((kv)[3]) + __half2float(*(__half*)&(t4).w) * pw;            \
    s += __shfl_xor(s, 1);                                                     \
    s += __shfl_xor(s, 2);                                                     \
    s += __shfl_xor(s, 4);                                                     \
    s += __shfl_xor(s, 8);                                                     \
    out_a = (okflag) ? (s + qb) * 0.125f : 0.f;                                \
  }

#define STATE_UPDATE(a, kv, okflag)                                            \
  {                                                                            \
    float ea;                                                                  \
    if ((a) > m) {                                                             \
      float sc = __expf(m - (a));                                              \
      denom *= sc;                                                             \
      acc0 *= sc; acc1 *= sc; acc2 *= sc; acc3 *= sc;                          \
      m = (a);                                                                 \
      ea = 1.0f;                                                               \
    } else {                                                                   \
      ea = __expf((a) - m);                                                    \
    }                                                                          \
    denom += ea;                                                               \
    if (okflag) {                                                              \
      acc0 += ea * bf2f((kv)[4]);                                              \
      acc1 += ea * bf2f((kv)[5]);                                              \
      acc2 += ea * bf2f((kv)[6]);                                              \
      acc3 += ea * bf2f((kv)[7]);                                              \
    }                                                                          \
  }

    int p = r0;
    for (; p + 3 < r1; p += 4) {
      int srcA = ssrc[p], srcB = ssrc[p + 1], srcC = ssrc[p + 2], srcD = ssrc[p + 3];
      bool okA = (unsigned)srcA < NN, okB = (unsigned)srcB < NN;
      bool okC = (unsigned)srcC < NN, okD = (unsigned)srcD < NN;
      if (!okA) srcA = 0;
      if (!okB) srcB = 0;
      if (!okC) srcC = 0;
      if (!okD) srcD = 0;
      u16x8 kvA = *(const u16x8*)(qkvp + (size_t)srcA * NB + kvoff);
      u16x8 kvB = *(const u16x8*)(qkvp + (size_t)srcB * NB + kvoff);
      u16x8 kvC = *(const u16x8*)(qkvp + (size_t)srcC * NB + kvoff);
      u16x8 kvD = *(const u16x8*)(qkvp + (size_t)srcD * NB + kvoff);
      ushort4 tA = *(const ushort4*)(te_s + (size_t)p * 64 + jb);
      ushort4 tB = *(const ushort4*)(te_s + (size_t)(p + 1) * 64 + jb);
      ushort4 tC = *(const ushort4*)(te_s + (size_t)(p + 2) * 64 + jb);
      ushort4 tD = *(const ushort4*)(te_s + (size_t)(p + 3) * 64 + jb);

      float aA, aB, aC, aD;
      ALPHA_OF(kvA, tA, aA, okA)
      ALPHA_OF(kvB, tB, aB, okB)
      ALPHA_OF(kvC, tC, aC, okC)
      ALPHA_OF(kvD, tD, aD, okD)
      STATE_UPDATE(aA, kvA, okA)
      STATE_UPDATE(aB, kvB, okB)
      STATE_UPDATE(aC, kvC, okC)
      STATE_UPDATE(aD, kvD, okD)
    }
    for (; p < r1; ++p) {
      int src = ssrc[p];
      bool ok = (unsigned)src < NN;
      if (!ok) src = 0;
      u16x8 kv = *(const u16x8*)(qkvp + (size_t)src * NB + kvoff);
      ushort4 t4 = *(const ushort4*)(te_s + (size_t)p * 64 + jb);
      float a;
      ALPHA_OF(kv, t4, a, ok)
      STATE_UPDATE(a, kv, ok)
    }
#undef ALPHA_OF
#undef STATE_UPDATE
  }

  // merge the two halves via LDS
  if (half == 1) {
    float* s = mrg[nslot][lane];
    s[0] = m; s[1] = denom; s[2] = acc0; s[3] = acc1; s[4] = acc2; s[5] = acc3;
  }
  __syncthreads();
  if (half == 0 && valid) {
    const float* s = mrg[nslot][lane];
    float mB = s[0], dB = s[1];
    float mM = fmaxf(m, mB);
    float d, a0, a1, a2, a3;
    if (mM == -INFINITY) {
      d = 0.f; a0 = a1 = a2 = a3 = 0.f;
    } else {
      float sA = (m == -INFINITY) ? 0.f : __expf(m - mM);
      float sB = (mB == -INFINITY) ? 0.f : __expf(mB - mM);
      d = denom * sA + dB * sB;
      a0 = acc0 * sA + s[2] * sB;
      a1 = acc1 * sA + s[3] * sB;
      a2 = acc2 * sA + s[4] * sB;
      a3 = acc3 * sA + s[5] * sB;
    }
    float inv = 1.f / (d + 1e-16f);
    ushort4 r;
    r.x = f2bf(fmaxf(a0 * inv, 0.f));
    r.y = f2bf(fmaxf(a1 * inv, 0.f));
    r.z = f2bf(fmaxf(a2 * inv, 0.f));
    r.w = f2bf(fmaxf(a3 * inv, 0.f));
    *(ushort4*)(xout + (size_t)n * HC + c) = r;
    if (DOY) {
      float yv = bf2f(r.x) * ldf(wc, c + 0, fbf);
      yv += bf2f(r.y) * ldf(wc, c + 1, fbf);
      yv += bf2f(r.z) * ldf(wc, c + 2, fbf);
      yv += bf2f(r.w) * ldf(wc, c + 3, fbf);
      for (int off = 32; off; off >>= 1) yv += __shfl_xor(yv, off);
      if (lane == 0) ynode[n] = yv;
    }
  }
}

// ---------------- out[e] = y[src] + y[dst] + bc ----------------
__global__ __launch_bounds__(256) void final2_kernel(
    const int* __restrict__ flags, const void* __restrict__ eidx,
    const float* __restrict__ y, const void* __restrict__ bc,
    void* __restrict__ out) {
  bool is64 = flags[0] != 0, fbf = flags[1] != 0;
  int e = blockIdx.x * 256 + threadIdx.x;
  if (e >= NE) return;
  int src = ldsrc(eidx, e, is64);
  int dst = lddst(eidx, e, is64);
  if ((unsigned)src >= NN) src = 0;
  if ((unsigned)dst >= NN) dst = 0;
  stout(out, e, y[src] + y[dst] + ldf(bc, 0, fbf), fbf);
}

extern "C" void kernel_launch(void* const* d_in, const int* in_sizes, int n_in,
                              void* d_out, int out_size, void* d_ws, size_t ws_size,
                              hipStream_t stream) {
  const void* eidx  = d_in[0];
  const void* rawt  = d_in[1];
  const void* noise = d_in[2];
  const void* nemb  = d_in[3];
  const void *wq1 = d_in[4],  *bq1 = d_in[5];
  const void *wk1 = d_in[6],  *bk1 = d_in[7];
  const void *wv1 = d_in[8],  *bv1 = d_in[9];
  const void *wt1 = d_in[10], *bt1 = d_in[11];
  const void *wq2 = d_in[12], *bq2 = d_in[13];
  const void *wk2 = d_in[14], *bk2 = d_in[15];
  const void *wv2 = d_in[16], *bv2 = d_in[17];
  const void *wt2 = d_in[18], *bt2 = d_in[19];
  const void *wcp = d_in[20], *bcp = d_in[21];

  char* ws = (char*)d_ws;
  size_t off = 0;
  auto alloc = [&](size_t bytes) -> void* {
    void* p = ws + off;
    off += (bytes + 255) & ~(size_t)255;
    return p;
  };
  int*   flags  = (int*)alloc(256);
  float* divt   = (float*)alloc(256);
  u16*   WtBig  = (u16*)alloc((size_t)NB * HC * 2);
  float* biasBig= (float*)alloc((size_t)NB * 4);
  u16*   qkvp   = (u16*)alloc((size_t)NN * NB * 2);
  u16*   x1     = (u16*)alloc((size_t)NN * HC * 2);
  u16*   x2     = (u16*)alloc((size_t)NN * HC * 2);
  float* ynode  = (float*)alloc((size_t)NN * 4);
  int* offsets  = (int*)alloc((size_t)(NN + 1) * 4);
  int* cursor   = (int*)alloc((size_t)NN * 4);
  int* bsum     = (int*)alloc(256 * 4);
  int* ssrc     = (int*)alloc((size_t)NE * 4);
  float* stt    = (float*)alloc((size_t)NE * 4);
  u16* te_s     = (u16*)alloc((size_t)NE * 64 * 2);
  size_t need = off;

  int gN = (NN + 255) / 256, gE = (NE + 255) / 256;
  int nb = (NN + 255) / 256;

  if (ws_size < 1024) {
    raw_sentinel_kernel<<<gE, 256, 0, stream>>>((u16*)d_out);
    return;
  }
  devinit_kernel<<<1, 64, 0, stream>>>(eidx, nemb, flags, divt);
  if (need > ws_size) {
    sentinel_kernel<<<gE, 256, 0, stream>>>(flags, d_out);
    return;
  }

  // CSR by dst (+ sorted src / time)
  zero_kernel<<<gN, 256, 0, stream>>>(cursor, NN);
  hist_kernel<<<gE, 256, 0, stream>>>(flags, eidx, cursor);
  scan1_kernel<<<nb, 256, 0, stream>>>(cursor, offsets, bsum, NN);
  scan2_kernel<<<1, 256, 0, stream>>>(bsum, offsets, nb, NN);
  scan3_kernel<<<nb, 256, 0, stream>>>(offsets, bsum, cursor, NN);
  fill_kernel<<<gE, 256, 0, stream>>>(flags, eidx, rawt, noise, cursor, ssrc, stt);

  int gTe = (NE * 32 + 255) / 256;
  te_kernel<<<gTe, 256, 0, stream>>>(stt, divt, te_s);

  dim3 ggemm((NN + 63) / 64, NB / 64);
  dim3 gt1(NIN / 64, 4, 3), gt2(HC / 64, 4, 3);
  int gNode2 = (NN + 1) / 2;

  // ---- Layer 1 (A = raw node_emb, K=128) ----
  transw3_kernel<<<gt1, 256, 0, stream>>>(flags, wq1, wk1, wv1, WtBig, NIN);
  wcombbias_kernel<<<260, 256, 0, stream>>>(flags, wt1, WtBig, WtBig + (size_t)768 * NIN,
                                            bq1, bk1, bv1, biasBig, NIN);
  gemm_mfma<false><<<ggemm, 256, 0, stream>>>(flags, nemb, WtBig, biasBig, qkvp, NN, NIN);
  aggfused_kernel<0><<<gNode2, 256, 0, stream>>>(flags, ssrc, offsets, te_s, qkvp, bt1,
                                                 x1, wcp, ynode);

  // ---- Layer 2 (A = bf16 x1, K=256) ----
  transw3_kernel<<<gt2, 256, 0, stream>>>(flags, wq2, wk2, wv2, WtBig, HC);
  wcombbias_kernel<<<260, 256, 0, stream>>>(flags, wt2, WtBig, WtBig + (size_t)768 * HC,
                                            bq2, bk2, bv2, biasBig, HC);
  gemm_mfma<true><<<ggemm, 256, 0, stream>>>(flags, x1, WtBig, biasBig, qkvp, NN, HC);
  aggfused_kernel<1><<<gNode2, 256, 0, stream>>>(flags, ssrc, offsets, te_s, qkvp, bt2,
                                                 x2, wcp, ynode);

  // Edge scorer epilogue
  final2_kernel<<<gE, 256, 0, stream>>>(flags, eidx, ynode, bcp, d_out);
}

// Round 17
// 394.153 us; speedup vs baseline: 1.0182x; 1.0182x over previous
//
#include <hip/hip_runtime.h>
#include <hip/hip_fp16.h>
#include <math.h>

// Problem constants
#define NN   20000     // nodes
#define NE   320000    // edges
#define NIN  128       // node input dim
#define HC   256       // heads(4) * hidden(64)
#define NB   1024      // fused GEMM output width: [q | kv-interleaved | qproj]

typedef unsigned short u16;
typedef __attribute__((ext_vector_type(8))) short bf16x8;
typedef __attribute__((ext_vector_type(8))) unsigned short u16x8;
typedef __attribute__((ext_vector_type(4))) float f32x4;

__device__ __forceinline__ float bf2f(u16 u) {
  union { unsigned int i; float f; } x;
  x.i = ((unsigned int)u) << 16;
  return x.f;
}
__device__ __forceinline__ u16 f2bf(float f) {
  union { float f; unsigned int i; } x;
  x.f = f;
  unsigned int r = x.i + 0x7fffu + ((x.i >> 16) & 1u);
  return (u16)(r >> 16);
}

// dtype-flexible loads (flags detected on device each launch)
__device__ __forceinline__ float ldf(const void* p, int i, bool fbf) {
  return fbf ? bf2f(((const u16*)p)[i]) : ((const float*)p)[i];
}
__device__ __forceinline__ int ldsrc(const void* p, int e, bool is64) {
  const int* p32 = (const int*)p;
  return is64 ? p32[2 * e] : p32[e];
}
__device__ __forceinline__ int lddst(const void* p, int e, bool is64) {
  const int* p32 = (const int*)p;
  return is64 ? p32[2 * (NE + e)] : p32[NE + e];
}
__device__ __forceinline__ void stout(void* p, int i, float v, bool fbf) {
  if (fbf) ((u16*)p)[i] = f2bf(v);
  else ((float*)p)[i] = v;
}

// async global->LDS, 16B per lane
__device__ __forceinline__ void gload_lds16(const u16* g, u16* l) {
  __builtin_amdgcn_global_load_lds(
      (const __attribute__((address_space(1))) void*)g,
      (__attribute__((address_space(3))) void*)l, 16, 0, 0);
}

// ---------------- detection + div_term init ----------------
__global__ void devinit_kernel(const void* __restrict__ eidx,
                               const void* __restrict__ nemb,
                               int* __restrict__ flags, float* __restrict__ divt) {
  int lane = threadIdx.x;
  if (lane < 32) {
    const float c32 = (float)(-0.14391156831212787);
    float prod = (float)(2 * lane) * c32;
    divt[lane] = (float)exp((double)prod);
  }
  if (lane == 0) {
    const int* p32 = (const int*)eidx;
    int is64 = 1;
    for (int i = 1; i < 128; i += 2)
      if (p32[i] != 0) { is64 = 0; break; }
    const u16* q16 = (const u16*)nemb;
    int fbf = 1;
    for (int i = 0; i < 128; i += 2) {
      unsigned e = (q16[i] >> 7) & 0xFF;
      if (e < 90 || e > 140) { fbf = 0; break; }
    }
    flags[0] = is64;
    flags[1] = fbf;
  }
}

__global__ void sentinel_kernel(const int* __restrict__ flags, void* __restrict__ out) {
  int i = blockIdx.x * 256 + threadIdx.x;
  if (i < NE) stout(out, i, 3000.0f, flags[1] != 0);
}
__global__ void raw_sentinel_kernel(u16* __restrict__ out) {
  int i = blockIdx.x * 256 + threadIdx.x;
  if (i < NE) out[i] = f2bf(3000.0f);
}

// ---------------- CSR build ----------------
__global__ void zero_kernel(int* __restrict__ p, int n) {
  int i = blockIdx.x * 256 + threadIdx.x;
  if (i < n) p[i] = 0;
}

__global__ void hist_kernel(const int* __restrict__ flags, const void* __restrict__ eidx,
                            int* __restrict__ cnt) {
  bool is64 = flags[0] != 0;
  int e = blockIdx.x * 256 + threadIdx.x;
  if (e < NE) {
    int d = lddst(eidx, e, is64);
    if ((unsigned)d < NN) atomicAdd(&cnt[d], 1);
  }
}

__global__ void scan1_kernel(const int* __restrict__ cnt, int* __restrict__ offs,
                             int* __restrict__ bsum, int n) {
  __shared__ int s[256];
  int b = blockIdx.x, t = threadIdx.x, i = b * 256 + t;
  int x = (i < n) ? cnt[i] : 0;
  s[t] = x;
  __syncthreads();
  for (int off = 1; off < 256; off <<= 1) {
    int y = (t >= off) ? s[t - off] : 0;
    __syncthreads();
    s[t] += y;
    __syncthreads();
  }
  if (i < n) offs[i] = s[t] - x;
  if (t == 255) bsum[b] = s[t];
}

__global__ void scan2_kernel(int* __restrict__ bsum, int* __restrict__ offs,
                             int nb, int n) {
  __shared__ int s[256];
  int t = threadIdx.x;
  int x = (t < nb) ? bsum[t] : 0;
  s[t] = x;
  __syncthreads();
  for (int off = 1; off < 256; off <<= 1) {
    int y = (t >= off) ? s[t - off] : 0;
    __syncthreads();
    s[t] += y;
    __syncthreads();
  }
  if (t < nb) bsum[t] = s[t] - x;
  if (t == 255) offs[n] = s[t];
}

__global__ void scan3_kernel(int* __restrict__ offs, const int* __restrict__ bsum,
                             int* __restrict__ cursor, int n) {
  int i = blockIdx.x * 256 + threadIdx.x;
  if (i < n) {
    int v = offs[i] + bsum[blockIdx.x];
    offs[i] = v;
    cursor[i] = v;
  }
}

__global__ void fill_kernel(const int* __restrict__ flags, const void* __restrict__ eidx,
                            const void* __restrict__ rawt, const void* __restrict__ noise,
                            int* __restrict__ cursor, int* __restrict__ ssrc,
                            float* __restrict__ stt) {
  bool is64 = flags[0] != 0, fbf = flags[1] != 0;
  int e = blockIdx.x * 256 + threadIdx.x;
  if (e < NE) {
    int d = lddst(eidx, e, is64);
    if ((unsigned)d < NN) {
      int pos = atomicAdd(&cursor[d], 1);
      if ((unsigned)pos < NE) {
        int src = ldsrc(eidx, e, is64);
        if ((unsigned)src >= NN) src = 0;
        ssrc[pos] = src;
        stt[pos] = ldf(rawt, e, fbf) + ldf(noise, e, fbf);
      }
    }
  }
}

// ---------------- te_s[p][64] (f16) — double range reduction + fast sincos --------
__global__ __launch_bounds__(256) void te_kernel(
    const float* __restrict__ stt, const float* __restrict__ divt,
    u16* __restrict__ te_s) {
  int idx = blockIdx.x * 256 + threadIdx.x;
  int p = idx >> 5;          // 32 freqs per edge
  if (p >= NE) return;
  int f = idx & 31;
  float tt = stt[p];
  float arg = tt * divt[f];
  // reduce the fp32 arg mod 2π in double (error ~1e-11 rad << f16 rounding)
  double rev = (double)arg * 0.15915494309189535;   // /(2π)
  double fr = rev - floor(rev);                     // [0,1)
  float red = (float)(fr * 6.283185307179586);      // [0,2π) — sincosf fast path
  float sv, cv;
  sincosf(red, &sv, &cv);
  __half hs = __float2half(sv), hc = __float2half(cv);
  unsigned int packed = (unsigned int)(*(u16*)&hs) | ((unsigned int)(*(u16*)&hc) << 16);
  ((unsigned int*)te_s)[(size_t)p * 32 + f] = packed;
}

// ---------------- merged weight transpose: 3 matrices -> WtBig rows 0/256/512 -----
__global__ void transw3_kernel(const int* __restrict__ flags, const void* __restrict__ W0,
                               const void* __restrict__ W1, const void* __restrict__ W2,
                               u16* __restrict__ WtBig, int K) {
  bool fbf = flags[1] != 0;
  __shared__ u16 tile[64][65];
  int z = blockIdx.z;
  const void* W = (z == 0) ? W0 : (z == 1) ? W1 : W2;
  u16* dst = WtBig + (size_t)z * 256 * K;
  int kb = blockIdx.x * 64, cb = blockIdx.y * 64;
  int tx = threadIdx.x & 63, ty = threadIdx.x >> 6;
  for (int i = ty; i < 64; i += 4)
    tile[tx][i] = f2bf(ldf(W, (kb + i) * HC + cb + tx, fbf));
  __syncthreads();
  for (int i = ty; i < 64; i += 4)
    dst[(size_t)(cb + i) * K + kb + tx] = tile[i][tx];
}

// ---------------- wcomb + biasBig merged ----------------
__global__ void wcombbias_kernel(const int* __restrict__ flags, const void* __restrict__ wt,
                                 const u16* __restrict__ Wqt, u16* __restrict__ Wout,
                                 const void* __restrict__ bq, const void* __restrict__ bk,
                                 const void* __restrict__ bv, float* __restrict__ biasBig,
                                 int K) {
  bool fbf = flags[1] != 0;
  int b = blockIdx.x, t = threadIdx.x;
  if (b < 256) {
    __shared__ float wrow[64];
    int j = b, h = j >> 6;
    if (t < 64) wrow[t] = ldf(wt, (j & 63) * HC + h * 64 + t, fbf);
    __syncthreads();
    if (t < K) {
      float s = 0.f;
#pragma unroll 8
      for (int mm = 0; mm < 64; ++mm)
        s += wrow[mm] * bf2f(Wqt[(size_t)(h * 64 + mm) * K + t]);
      Wout[(size_t)j * K + t] = f2bf(s);
    }
  } else if (b < 259) {
    int bb = b - 256;
    const void* p = (bb == 0) ? bq : (bb == 1) ? bk : bv;
    biasBig[bb * 256 + t] = ldf(p, t, fbf);
  } else {
    int j = t, h = j >> 6;
    float s = 0.f;
    for (int mm = 0; mm < 64; ++mm)
      s += ldf(bq, h * 64 + mm, fbf) * ldf(wt, (j & 63) * HC + h * 64 + mm, fbf);
    biasBig[768 + j] = s;
  }
}

// ---------------- fused MFMA GEMM (direct-to-LDS, swizzled, kv-interleave) --------
template <bool AWS>
__global__ __launch_bounds__(256) void gemm_mfma(
    const int* __restrict__ flags, const void* __restrict__ Ap,
    const u16* __restrict__ Wt, const float* __restrict__ bias,
    u16* __restrict__ C, int M, int K) {
  bool fbf = flags[1] != 0;
  __shared__ u16 As[64 * 32];
  __shared__ u16 Bs[64 * 32];
  int tid = threadIdx.x;
  int rb = blockIdx.x * 64, cb = blockIdx.y * 64;
  int wave = tid >> 6, lane = tid & 63;
  int l15 = lane & 15, quad = lane >> 4;

  f32x4 acc[4];
#pragma unroll
  for (int mt = 0; mt < 4; ++mt)
#pragma unroll
    for (int r = 0; r < 4; ++r) acc[mt][r] = 0.f;

  int srow = tid >> 2;
  int schunk = tid & 3;
  int gchunk = schunk ^ (srow & 3);
  int arow = rb + srow; if (arow >= M) arow = M - 1;
  u16* asl = &As[srow * 32 + schunk * 8];
  u16* bsl = &Bs[srow * 32 + schunk * 8];
  const u16* bsrc = Wt + (size_t)(cb + srow) * K + gchunk * 8;
  const bool adirect = AWS || fbf;
  const u16* asrc = adirect ? ((const u16*)Ap + (size_t)arow * K + gchunk * 8) : (const u16*)0;

  for (int kk = 0; kk < K; kk += 32) {
    if (adirect) {
      gload_lds16(asrc + kk, asl);
    } else {
      const float* A = (const float*)Ap + (size_t)arow * K + kk + gchunk * 8;
      bf16x8 tmp;
#pragma unroll
      for (int i = 0; i < 8; ++i) tmp[i] = (short)f2bf(A[i]);
      *(bf16x8*)asl = tmp;
    }
    gload_lds16(bsrc + kk, bsl);
    __syncthreads();

    int bcol = wave * 16 + l15;
    bf16x8 bfrag = *(const bf16x8*)&Bs[bcol * 32 + ((quad ^ (bcol & 3)) * 8)];
#pragma unroll
    for (int mt = 0; mt < 4; ++mt) {
      int ar = mt * 16 + l15;
      bf16x8 afrag = *(const bf16x8*)&As[ar * 32 + ((quad ^ (ar & 3)) * 8)];
      acc[mt] = __builtin_amdgcn_mfma_f32_16x16x32_bf16(afrag, bfrag, acc[mt], 0, 0, 0);
    }
    __syncthreads();
  }

  int gcol = cb + wave * 16 + l15;
  float bv = bias[gcol];
  int scol;
  if (gcol < 256) scol = gcol;
  else if (gcol < 512) { int cc = gcol - 256; scol = 256 + ((cc >> 2) << 3) + (cc & 3); }
  else if (gcol < 768) { int cc = gcol - 512; scol = 256 + ((cc >> 2) << 3) + 4 + (cc & 3); }
  else scol = gcol;
#pragma unroll
  for (int mt = 0; mt < 4; ++mt) {
#pragma unroll
    for (int r = 0; r < 4; ++r) {
      int grow = rb + mt * 16 + quad * 4 + r;
      if (grow < M) C[(size_t)grow * NB + scol] = f2bf(acc[mt][r] + bv);
    }
  }
}

// ---------------- fused alpha + ONLINE softmax + aggregation + relu, 4-edge unroll --
// One wave per node (R15 measured-best shape). qbt folded in.
// DOY: fold edge-scorer projection y[n]=x[n].wc into the epilogue (layer 2).
template <int DOY>
__global__ __launch_bounds__(256) void aggfused_kernel(
    const int* __restrict__ flags, const int* __restrict__ ssrc,
    const int* __restrict__ offsets, const u16* __restrict__ te_s,
    const u16* __restrict__ qkvp, const void* __restrict__ bt,
    u16* __restrict__ xout, const void* __restrict__ wc,
    float* __restrict__ ynode) {
  bool fbf = flags[1] != 0;
  int w = threadIdx.x >> 6;
  int n = blockIdx.x * 4 + w;
  if (n >= NN) return;
  int lane = threadIdx.x & 63;
  int c = lane * 4;
  int s0 = offsets[n], s1 = offsets[n + 1];
  if (s0 < 0) s0 = 0;
  if (s1 > NE) s1 = NE;

  ushort4 q4 = *(const ushort4*)(qkvp + (size_t)n * NB + c);
  ushort4 p4 = *(const ushort4*)(qkvp + (size_t)n * NB + 768 + c);
  float qx = bf2f(q4.x), qy = bf2f(q4.y), qz = bf2f(q4.z), qw = bf2f(q4.w);
  float px = bf2f(p4.x), py = bf2f(p4.y), pz = bf2f(p4.z), pw = bf2f(p4.w);
  // qbt inline: Σ_c q[c]*bt[c] over this head's 16 lanes
  float pb = qx * ldf(bt, c + 0, fbf);
  pb += qy * ldf(bt, c + 1, fbf);
  pb += qz * ldf(bt, c + 2, fbf);
  pb += qw * ldf(bt, c + 3, fbf);
  pb += __shfl_xor(pb, 1);
  pb += __shfl_xor(pb, 2);
  pb += __shfl_xor(pb, 4);
  pb += __shfl_xor(pb, 8);
  float qb = pb;
  int jb = c & 63;
  int kvoff = 256 + lane * 8;

  float m = -INFINITY, denom = 0.f;
  float acc0 = 0.f, acc1 = 0.f, acc2 = 0.f, acc3 = 0.f;

#define ALPHA_OF(kv, t4, out_a, okflag)                                        \
  {                                                                            \
    float s = qx * bf2f((kv)[0]) + __half2float(*(__half*)&(t4).x) * px;       \
    s += qy * bf2f((kv)[1]) + __half2float(*(__half*)&(t4).y) * py;            \
    s += qz * bf2f((kv)[2]) + __half2float(*(__half*)&(t4).z) * pz;            \
    s += qw * bf2f((kv)[3]) + __half2float(*(__half*)&(t4).w) * pw;            \
    s += __shfl_xor(s, 1);                                                     \
    s += __shfl_xor(s, 2);                                                     \
    s += __shfl_xor(s, 4);                                                     \
    s += __shfl_xor(s, 8);                                                     \
    out_a = (okflag) ? (s + qb) * 0.125f : 0.f;                                \
  }

#define STATE_UPDATE(a, kv, okflag)                                            \
  {                                                                            \
    float ea;                                                                  \
    if ((a) > m) {                                                             \
      float sc = __expf(m - (a));                                              \
      denom *= sc;                                                             \
      acc0 *= sc; acc1 *= sc; acc2 *= sc; acc3 *= sc;                          \
      m = (a);                                                                 \
      ea = 1.0f;                                                               \
    } else {                                                                   \
      ea = __expf((a) - m);                                                    \
    }                                                                          \
    denom += ea;                                                               \
    if (okflag) {                                                              \
      acc0 += ea * bf2f((kv)[4]);                                              \
      acc1 += ea * bf2f((kv)[5]);                                              \
      acc2 += ea * bf2f((kv)[6]);                                              \
      acc3 += ea * bf2f((kv)[7]);                                              \
    }                                                                          \
  }

  int p = s0;
  for (; p + 3 < s1; p += 4) {
    int srcA = ssrc[p], srcB = ssrc[p + 1], srcC = ssrc[p + 2], srcD = ssrc[p + 3];
    bool okA = (unsigned)srcA < NN, okB = (unsigned)srcB < NN;
    bool okC = (unsigned)srcC < NN, okD = (unsigned)srcD < NN;
    if (!okA) srcA = 0;
    if (!okB) srcB = 0;
    if (!okC) srcC = 0;
    if (!okD) srcD = 0;
    u16x8 kvA = *(const u16x8*)(qkvp + (size_t)srcA * NB + kvoff);
    u16x8 kvB = *(const u16x8*)(qkvp + (size_t)srcB * NB + kvoff);
    u16x8 kvC = *(const u16x8*)(qkvp + (size_t)srcC * NB + kvoff);
    u16x8 kvD = *(const u16x8*)(qkvp + (size_t)srcD * NB + kvoff);
    ushort4 tA = *(const ushort4*)(te_s + (size_t)p * 64 + jb);
    ushort4 tB = *(const ushort4*)(te_s + (size_t)(p + 1) * 64 + jb);
    ushort4 tC = *(const ushort4*)(te_s + (size_t)(p + 2) * 64 + jb);
    ushort4 tD = *(const ushort4*)(te_s + (size_t)(p + 3) * 64 + jb);

    float aA, aB, aC, aD;
    ALPHA_OF(kvA, tA, aA, okA)
    ALPHA_OF(kvB, tB, aB, okB)
    ALPHA_OF(kvC, tC, aC, okC)
    ALPHA_OF(kvD, tD, aD, okD)
    STATE_UPDATE(aA, kvA, okA)
    STATE_UPDATE(aB, kvB, okB)
    STATE_UPDATE(aC, kvC, okC)
    STATE_UPDATE(aD, kvD, okD)
  }
  for (; p < s1; ++p) {
    int src = ssrc[p];
    bool ok = (unsigned)src < NN;
    if (!ok) src = 0;
    u16x8 kv = *(const u16x8*)(qkvp + (size_t)src * NB + kvoff);
    ushort4 t4 = *(const ushort4*)(te_s + (size_t)p * 64 + jb);
    float a;
    ALPHA_OF(kv, t4, a, ok)
    STATE_UPDATE(a, kv, ok)
  }
#undef ALPHA_OF
#undef STATE_UPDATE

  float inv = 1.f / (denom + 1e-16f);
  ushort4 r;
  r.x = f2bf(fmaxf(acc0 * inv, 0.f));
  r.y = f2bf(fmaxf(acc1 * inv, 0.f));
  r.z = f2bf(fmaxf(acc2 * inv, 0.f));
  r.w = f2bf(fmaxf(acc3 * inv, 0.f));
  *(ushort4*)(xout + (size_t)n * HC + c) = r;
  if (DOY) {
    float yv = bf2f(r.x) * ldf(wc, c + 0, fbf);
    yv += bf2f(r.y) * ldf(wc, c + 1, fbf);
    yv += bf2f(r.z) * ldf(wc, c + 2, fbf);
    yv += bf2f(r.w) * ldf(wc, c + 3, fbf);
    for (int off = 32; off; off >>= 1) yv += __shfl_xor(yv, off);
    if (lane == 0) ynode[n] = yv;
  }
}

// ---------------- out[e] = y[src] + y[dst] + bc ----------------
__global__ __launch_bounds__(256) void final2_kernel(
    const int* __restrict__ flags, const void* __restrict__ eidx,
    const float* __restrict__ y, const void* __restrict__ bc,
    void* __restrict__ out) {
  bool is64 = flags[0] != 0, fbf = flags[1] != 0;
  int e = blockIdx.x * 256 + threadIdx.x;
  if (e >= NE) return;
  int src = ldsrc(eidx, e, is64);
  int dst = lddst(eidx, e, is64);
  if ((unsigned)src >= NN) src = 0;
  if ((unsigned)dst >= NN) dst = 0;
  stout(out, e, y[src] + y[dst] + ldf(bc, 0, fbf), fbf);
}

extern "C" void kernel_launch(void* const* d_in, const int* in_sizes, int n_in,
                              void* d_out, int out_size, void* d_ws, size_t ws_size,
                              hipStream_t stream) {
  const void* eidx  = d_in[0];
  const void* rawt  = d_in[1];
  const void* noise = d_in[2];
  const void* nemb  = d_in[3];
  const void *wq1 = d_in[4],  *bq1 = d_in[5];
  const void *wk1 = d_in[6],  *bk1 = d_in[7];
  const void *wv1 = d_in[8],  *bv1 = d_in[9];
  const void *wt1 = d_in[10], *bt1 = d_in[11];
  const void *wq2 = d_in[12], *bq2 = d_in[13];
  const void *wk2 = d_in[14], *bk2 = d_in[15];
  const void *wv2 = d_in[16], *bv2 = d_in[17];
  const void *wt2 = d_in[18], *bt2 = d_in[19];
  const void *wcp = d_in[20], *bcp = d_in[21];

  char* ws = (char*)d_ws;
  size_t off = 0;
  auto alloc = [&](size_t bytes) -> void* {
    void* p = ws + off;
    off += (bytes + 255) & ~(size_t)255;
    return p;
  };
  int*   flags  = (int*)alloc(256);
  float* divt   = (float*)alloc(256);
  u16*   WtBig  = (u16*)alloc((size_t)NB * HC * 2);
  float* biasBig= (float*)alloc((size_t)NB * 4);
  u16*   qkvp   = (u16*)alloc((size_t)NN * NB * 2);
  u16*   x1     = (u16*)alloc((size_t)NN * HC * 2);
  u16*   x2     = (u16*)alloc((size_t)NN * HC * 2);
  float* ynode  = (float*)alloc((size_t)NN * 4);
  int* offsets  = (int*)alloc((size_t)(NN + 1) * 4);
  int* cursor   = (int*)alloc((size_t)NN * 4);
  int* bsum     = (int*)alloc(256 * 4);
  int* ssrc     = (int*)alloc((size_t)NE * 4);
  float* stt    = (float*)alloc((size_t)NE * 4);
  u16* te_s     = (u16*)alloc((size_t)NE * 64 * 2);
  size_t need = off;

  int gN = (NN + 255) / 256, gE = (NE + 255) / 256;
  int nb = (NN + 255) / 256;

  if (ws_size < 1024) {
    raw_sentinel_kernel<<<gE, 256, 0, stream>>>((u16*)d_out);
    return;
  }
  devinit_kernel<<<1, 64, 0, stream>>>(eidx, nemb, flags, divt);
  if (need > ws_size) {
    sentinel_kernel<<<gE, 256, 0, stream>>>(flags, d_out);
    return;
  }

  // CSR by dst (+ sorted src / time)
  zero_kernel<<<gN, 256, 0, stream>>>(cursor, NN);
  hist_kernel<<<gE, 256, 0, stream>>>(flags, eidx, cursor);
  scan1_kernel<<<nb, 256, 0, stream>>>(cursor, offsets, bsum, NN);
  scan2_kernel<<<1, 256, 0, stream>>>(bsum, offsets, nb, NN);
  scan3_kernel<<<nb, 256, 0, stream>>>(offsets, bsum, cursor, NN);
  fill_kernel<<<gE, 256, 0, stream>>>(flags, eidx, rawt, noise, cursor, ssrc, stt);

  int gTe = (NE * 32 + 255) / 256;
  te_kernel<<<gTe, 256, 0, stream>>>(stt, divt, te_s);

  dim3 ggemm((NN + 63) / 64, NB / 64);
  dim3 gt1(NIN / 64, 4, 3), gt2(HC / 64, 4, 3);
  int gNode = (NN + 3) / 4;

  // ---- Layer 1 (A = raw node_emb, K=128) ----
  transw3_kernel<<<gt1, 256, 0, stream>>>(flags, wq1, wk1, wv1, WtBig, NIN);
  wcombbias_kernel<<<260, 256, 0, stream>>>(flags, wt1, WtBig, WtBig + (size_t)768 * NIN,
                                            bq1, bk1, bv1, biasBig, NIN);
  gemm_mfma<false><<<ggemm, 256, 0, stream>>>(flags, nemb, WtBig, biasBig, qkvp, NN, NIN);
  aggfused_kernel<0><<<gNode, 256, 0, stream>>>(flags, ssrc, offsets, te_s, qkvp, bt1,
                                                x1, wcp, ynode);

  // ---- Layer 2 (A = bf16 x1, K=256) ----
  transw3_kernel<<<gt2, 256, 0, stream>>>(flags, wq2, wk2, wv2, WtBig, HC);
  wcombbias_kernel<<<260, 256, 0, stream>>>(flags, wt2, WtBig, WtBig + (size_t)768 * HC,
                                            bq2, bk2, bv2, biasBig, HC);
  gemm_mfma<true><<<ggemm, 256, 0, stream>>>(flags, x1, WtBig, biasBig, qkvp, NN, HC);
  aggfused_kernel<1><<<gNode, 256, 0, stream>>>(flags, ssrc, offsets, te_s, qkvp, bt2,
                                                x2, wcp, ynode);

  // Edge scorer epilogue
  final2_kernel<<<gE, 256, 0, stream>>>(flags, eidx, ynode, bcp, d_out);
}

// Round 18
// 393.790 us; speedup vs baseline: 1.0191x; 1.0009x over previous
//
#include <hip/hip_runtime.h>
#include <hip/hip_fp16.h>
#include <math.h>

// Problem constants
#define NN   20000     // nodes
#define NE   320000    // edges
#define NIN  128       // node input dim
#define HC   256       // heads(4) * hidden(64)
#define NB   1024      // fused GEMM output width: [q | kv-interleaved | qproj]

typedef unsigned short u16;
typedef __attribute__((ext_vector_type(8))) short bf16x8;
typedef __attribute__((ext_vector_type(8))) unsigned short u16x8;
typedef __attribute__((ext_vector_type(4))) float f32x4;

__device__ __forceinline__ float bf2f(u16 u) {
  union { unsigned int i; float f; } x;
  x.i = ((unsigned int)u) << 16;
  return x.f;
}
__device__ __forceinline__ u16 f2bf(float f) {
  union { float f; unsigned int i; } x;
  x.f = f;
  unsigned int r = x.i + 0x7fffu + ((x.i >> 16) & 1u);
  return (u16)(r >> 16);
}

// dtype-flexible loads (flags detected on device each launch)
__device__ __forceinline__ float ldf(const void* p, int i, bool fbf) {
  return fbf ? bf2f(((const u16*)p)[i]) : ((const float*)p)[i];
}
__device__ __forceinline__ int ldsrc(const void* p, int e, bool is64) {
  const int* p32 = (const int*)p;
  return is64 ? p32[2 * e] : p32[e];
}
__device__ __forceinline__ int lddst(const void* p, int e, bool is64) {
  const int* p32 = (const int*)p;
  return is64 ? p32[2 * (NE + e)] : p32[NE + e];
}
__device__ __forceinline__ void stout(void* p, int i, float v, bool fbf) {
  if (fbf) ((u16*)p)[i] = f2bf(v);
  else ((float*)p)[i] = v;
}

// async global->LDS, 16B per lane
__device__ __forceinline__ void gload_lds16(const u16* g, u16* l) {
  __builtin_amdgcn_global_load_lds(
      (const __attribute__((address_space(1))) void*)g,
      (__attribute__((address_space(3))) void*)l, 16, 0, 0);
}

// ---------------- detection + div_term init ----------------
__global__ void devinit_kernel(const void* __restrict__ eidx,
                               const void* __restrict__ nemb,
                               int* __restrict__ flags, float* __restrict__ divt) {
  int lane = threadIdx.x;
  if (lane < 32) {
    const float c32 = (float)(-0.14391156831212787);
    float prod = (float)(2 * lane) * c32;
    divt[lane] = (float)exp((double)prod);
  }
  if (lane == 0) {
    const int* p32 = (const int*)eidx;
    int is64 = 1;
    for (int i = 1; i < 128; i += 2)
      if (p32[i] != 0) { is64 = 0; break; }
    const u16* q16 = (const u16*)nemb;
    int fbf = 1;
    for (int i = 0; i < 128; i += 2) {
      unsigned e = (q16[i] >> 7) & 0xFF;
      if (e < 90 || e > 140) { fbf = 0; break; }
    }
    flags[0] = is64;
    flags[1] = fbf;
  }
}

__global__ void sentinel_kernel(const int* __restrict__ flags, void* __restrict__ out) {
  int i = blockIdx.x * 256 + threadIdx.x;
  if (i < NE) stout(out, i, 3000.0f, flags[1] != 0);
}
__global__ void raw_sentinel_kernel(u16* __restrict__ out) {
  int i = blockIdx.x * 256 + threadIdx.x;
  if (i < NE) out[i] = f2bf(3000.0f);
}

// ---------------- CSR build ----------------
__global__ void zero_kernel(int* __restrict__ p, int n) {
  int i = blockIdx.x * 256 + threadIdx.x;
  if (i < n) p[i] = 0;
}

__global__ void hist_kernel(const int* __restrict__ flags, const void* __restrict__ eidx,
                            int* __restrict__ cnt) {
  bool is64 = flags[0] != 0;
  int e = blockIdx.x * 256 + threadIdx.x;
  if (e < NE) {
    int d = lddst(eidx, e, is64);
    if ((unsigned)d < NN) atomicAdd(&cnt[d], 1);
  }
}

__global__ void scan1_kernel(const int* __restrict__ cnt, int* __restrict__ offs,
                             int* __restrict__ bsum, int n) {
  __shared__ int s[256];
  int b = blockIdx.x, t = threadIdx.x, i = b * 256 + t;
  int x = (i < n) ? cnt[i] : 0;
  s[t] = x;
  __syncthreads();
  for (int off = 1; off < 256; off <<= 1) {
    int y = (t >= off) ? s[t - off] : 0;
    __syncthreads();
    s[t] += y;
    __syncthreads();
  }
  if (i < n) offs[i] = s[t] - x;
  if (t == 255) bsum[b] = s[t];
}

__global__ void scan2_kernel(int* __restrict__ bsum, int* __restrict__ offs,
                             int nb, int n) {
  __shared__ int s[256];
  int t = threadIdx.x;
  int x = (t < nb) ? bsum[t] : 0;
  s[t] = x;
  __syncthreads();
  for (int off = 1; off < 256; off <<= 1) {
    int y = (t >= off) ? s[t - off] : 0;
    __syncthreads();
    s[t] += y;
    __syncthreads();
  }
  if (t < nb) bsum[t] = s[t] - x;
  if (t == 255) offs[n] = s[t];
}

__global__ void scan3_kernel(int* __restrict__ offs, const int* __restrict__ bsum,
                             int* __restrict__ cursor, int n) {
  int i = blockIdx.x * 256 + threadIdx.x;
  if (i < n) {
    int v = offs[i] + bsum[blockIdx.x];
    offs[i] = v;
    cursor[i] = v;
  }
}

__global__ void fill_kernel(const int* __restrict__ flags, const void* __restrict__ eidx,
                            const void* __restrict__ rawt, const void* __restrict__ noise,
                            int* __restrict__ cursor, int* __restrict__ ssrc,
                            float* __restrict__ stt) {
  bool is64 = flags[0] != 0, fbf = flags[1] != 0;
  int e = blockIdx.x * 256 + threadIdx.x;
  if (e < NE) {
    int d = lddst(eidx, e, is64);
    if ((unsigned)d < NN) {
      int pos = atomicAdd(&cursor[d], 1);
      if ((unsigned)pos < NE) {
        int src = ldsrc(eidx, e, is64);
        if ((unsigned)src >= NN) src = 0;
        ssrc[pos] = src;
        stt[pos] = ldf(rawt, e, fbf) + ldf(noise, e, fbf);
      }
    }
  }
}

// ---------------- te_s[p][64] (f16) — double range reduction + fast sincos --------
__global__ __launch_bounds__(256) void te_kernel(
    const float* __restrict__ stt, const float* __restrict__ divt,
    u16* __restrict__ te_s) {
  int idx = blockIdx.x * 256 + threadIdx.x;
  int p = idx >> 5;          // 32 freqs per edge
  if (p >= NE) return;
  int f = idx & 31;
  float tt = stt[p];
  float arg = tt * divt[f];
  double rev = (double)arg * 0.15915494309189535;   // /(2π)
  double fr = rev - floor(rev);                     // [0,1)
  float red = (float)(fr * 6.283185307179586);      // [0,2π)
  float sv, cv;
  sincosf(red, &sv, &cv);
  __half hs = __float2half(sv), hc = __float2half(cv);
  unsigned int packed = (unsigned int)(*(u16*)&hs) | ((unsigned int)(*(u16*)&hc) << 16);
  ((unsigned int*)te_s)[(size_t)p * 32 + f] = packed;
}

// ---------------- merged weight transpose: 3 matrices -> WtBig rows 0/256/512 -----
__global__ void transw3_kernel(const int* __restrict__ flags, const void* __restrict__ W0,
                               const void* __restrict__ W1, const void* __restrict__ W2,
                               u16* __restrict__ WtBig, int K) {
  bool fbf = flags[1] != 0;
  __shared__ u16 tile[64][65];
  int z = blockIdx.z;
  const void* W = (z == 0) ? W0 : (z == 1) ? W1 : W2;
  u16* dst = WtBig + (size_t)z * 256 * K;
  int kb = blockIdx.x * 64, cb = blockIdx.y * 64;
  int tx = threadIdx.x & 63, ty = threadIdx.x >> 6;
  for (int i = ty; i < 64; i += 4)
    tile[tx][i] = f2bf(ldf(W, (kb + i) * HC + cb + tx, fbf));
  __syncthreads();
  for (int i = ty; i < 64; i += 4)
    dst[(size_t)(cb + i) * K + kb + tx] = tile[i][tx];
}

// ---------------- wcomb + biasBig merged ----------------
__global__ void wcombbias_kernel(const int* __restrict__ flags, const void* __restrict__ wt,
                                 const u16* __restrict__ Wqt, u16* __restrict__ Wout,
                                 const void* __restrict__ bq, const void* __restrict__ bk,
                                 const void* __restrict__ bv, float* __restrict__ biasBig,
                                 int K) {
  bool fbf = flags[1] != 0;
  int b = blockIdx.x, t = threadIdx.x;
  if (b < 256) {
    __shared__ float wrow[64];
    int j = b, h = j >> 6;
    if (t < 64) wrow[t] = ldf(wt, (j & 63) * HC + h * 64 + t, fbf);
    __syncthreads();
    if (t < K) {
      float s = 0.f;
#pragma unroll 8
      for (int mm = 0; mm < 64; ++mm)
        s += wrow[mm] * bf2f(Wqt[(size_t)(h * 64 + mm) * K + t]);
      Wout[(size_t)j * K + t] = f2bf(s);
    }
  } else if (b < 259) {
    int bb = b - 256;
    const void* p = (bb == 0) ? bq : (bb == 1) ? bk : bv;
    biasBig[bb * 256 + t] = ldf(p, t, fbf);
  } else {
    int j = t, h = j >> 6;
    float s = 0.f;
    for (int mm = 0; mm < 64; ++mm)
      s += ldf(bq, h * 64 + mm, fbf) * ldf(wt, (j & 63) * HC + h * 64 + mm, fbf);
    biasBig[768 + j] = s;
  }
}

// ---------------- fused MFMA GEMM — 128x128 tile (m97-style) ----------------------
// 4 waves; wave w owns rows (w>>1)*64..+64, cols (w&1)*64..+64 of the block tile:
// 4x4 16x16x32 MFMAs per K-step (16 MFMA vs 4 staging loads). Direct-to-LDS with
// XOR chunk swizzle. Same K order / fragment mapping as before -> bit-identical.
template <bool AWS>
__global__ __launch_bounds__(256) void gemm_mfma(
    const int* __restrict__ flags, const void* __restrict__ Ap,
    const u16* __restrict__ Wt, const float* __restrict__ bias,
    u16* __restrict__ C, int M, int K) {
  bool fbf = flags[1] != 0;
  __shared__ u16 As[128 * 32];
  __shared__ u16 Bs[128 * 32];
  int tid = threadIdx.x;
  int rb = blockIdx.x * 128, cb = blockIdx.y * 128;
  int wave = tid >> 6, lane = tid & 63;
  int l15 = lane & 15, quad = lane >> 4;
  int mbase = (wave >> 1) * 64, nbase = (wave & 1) * 64;

  f32x4 acc[4][4];
#pragma unroll
  for (int mt = 0; mt < 4; ++mt)
#pragma unroll
    for (int nt = 0; nt < 4; ++nt)
#pragma unroll
      for (int r = 0; r < 4; ++r) acc[mt][nt][r] = 0.f;

  // staging slots: sidx = tid and tid+256; srow = sidx>>2 (0..127), schunk = sidx&3
  int srow0 = tid >> 2, schunk0 = tid & 3;
  int srow1 = (tid + 256) >> 2, schunk1 = (tid + 256) & 3;
  int gchunk0 = schunk0 ^ (srow0 & 3);
  int gchunk1 = schunk1 ^ (srow1 & 3);
  int arow0 = rb + srow0; if (arow0 >= M) arow0 = M - 1;
  int arow1 = rb + srow1; if (arow1 >= M) arow1 = M - 1;
  u16* asl0 = &As[srow0 * 32 + schunk0 * 8];
  u16* asl1 = &As[srow1 * 32 + schunk1 * 8];
  u16* bsl0 = &Bs[srow0 * 32 + schunk0 * 8];
  u16* bsl1 = &Bs[srow1 * 32 + schunk1 * 8];
  const u16* bsrc0 = Wt + (size_t)(cb + srow0) * K + gchunk0 * 8;
  const u16* bsrc1 = Wt + (size_t)(cb + srow1) * K + gchunk1 * 8;
  const bool adirect = AWS || fbf;
  const u16* asrc0 = adirect ? ((const u16*)Ap + (size_t)arow0 * K + gchunk0 * 8) : (const u16*)0;
  const u16* asrc1 = adirect ? ((const u16*)Ap + (size_t)arow1 * K + gchunk1 * 8) : (const u16*)0;

  for (int kk = 0; kk < K; kk += 32) {
    if (adirect) {
      gload_lds16(asrc0 + kk, asl0);
      gload_lds16(asrc1 + kk, asl1);
    } else {
      const float* A0 = (const float*)Ap + (size_t)arow0 * K + kk + gchunk0 * 8;
      const float* A1 = (const float*)Ap + (size_t)arow1 * K + kk + gchunk1 * 8;
      bf16x8 t0, t1;
#pragma unroll
      for (int i = 0; i < 8; ++i) { t0[i] = (short)f2bf(A0[i]); t1[i] = (short)f2bf(A1[i]); }
      *(bf16x8*)asl0 = t0;
      *(bf16x8*)asl1 = t1;
    }
    gload_lds16(bsrc0 + kk, bsl0);
    gload_lds16(bsrc1 + kk, bsl1);
    __syncthreads();

    bf16x8 bfrag[4];
#pragma unroll
    for (int nt = 0; nt < 4; ++nt) {
      int col = nbase + nt * 16 + l15;
      bfrag[nt] = *(const bf16x8*)&Bs[col * 32 + ((quad ^ (col & 3)) * 8)];
    }
#pragma unroll
    for (int mt = 0; mt < 4; ++mt) {
      int row = mbase + mt * 16 + l15;
      bf16x8 afrag = *(const bf16x8*)&As[row * 32 + ((quad ^ (row & 3)) * 8)];
#pragma unroll
      for (int nt = 0; nt < 4; ++nt)
        acc[mt][nt] = __builtin_amdgcn_mfma_f32_16x16x32_bf16(afrag, bfrag[nt], acc[mt][nt], 0, 0, 0);
    }
    __syncthreads();
  }

#pragma unroll
  for (int nt = 0; nt < 4; ++nt) {
    int gcol = cb + nbase + nt * 16 + l15;
    float bv = bias[gcol];
    int scol;
    if (gcol < 256) scol = gcol;
    else if (gcol < 512) { int cc = gcol - 256; scol = 256 + ((cc >> 2) << 3) + (cc & 3); }
    else if (gcol < 768) { int cc = gcol - 512; scol = 256 + ((cc >> 2) << 3) + 4 + (cc & 3); }
    else scol = gcol;
#pragma unroll
    for (int mt = 0; mt < 4; ++mt) {
#pragma unroll
      for (int r = 0; r < 4; ++r) {
        int grow = rb + mbase + mt * 16 + quad * 4 + r;
        if (grow < M) C[(size_t)grow * NB + scol] = f2bf(acc[mt][nt][r] + bv);
      }
    }
  }
}

// ---------------- fused alpha + ONLINE softmax + aggregation + relu, 4-edge unroll --
// One wave per node. qbt folded in. DOY: fold y[n]=x[n].wc into epilogue (layer 2).
template <int DOY>
__global__ __launch_bounds__(256) void aggfused_kernel(
    const int* __restrict__ flags, const int* __restrict__ ssrc,
    const int* __restrict__ offsets, const u16* __restrict__ te_s,
    const u16* __restrict__ qkvp, const void* __restrict__ bt,
    u16* __restrict__ xout, const void* __restrict__ wc,
    float* __restrict__ ynode) {
  bool fbf = flags[1] != 0;
  int w = threadIdx.x >> 6;
  int n = blockIdx.x * 4 + w;
  if (n >= NN) return;
  int lane = threadIdx.x & 63;
  int c = lane * 4;
  int s0 = offsets[n], s1 = offsets[n + 1];
  if (s0 < 0) s0 = 0;
  if (s1 > NE) s1 = NE;

  ushort4 q4 = *(const ushort4*)(qkvp + (size_t)n * NB + c);
  ushort4 p4 = *(const ushort4*)(qkvp + (size_t)n * NB + 768 + c);
  float qx = bf2f(q4.x), qy = bf2f(q4.y), qz = bf2f(q4.z), qw = bf2f(q4.w);
  float px = bf2f(p4.x), py = bf2f(p4.y), pz = bf2f(p4.z), pw = bf2f(p4.w);
  float pb = qx * ldf(bt, c + 0, fbf);
  pb += qy * ldf(bt, c + 1, fbf);
  pb += qz * ldf(bt, c + 2, fbf);
  pb += qw * ldf(bt, c + 3, fbf);
  pb += __shfl_xor(pb, 1);
  pb += __shfl_xor(pb, 2);
  pb += __shfl_xor(pb, 4);
  pb += __shfl_xor(pb, 8);
  float qb = pb;
  int jb = c & 63;
  int kvoff = 256 + lane * 8;

  float m = -INFINITY, denom = 0.f;
  float acc0 = 0.f, acc1 = 0.f, acc2 = 0.f, acc3 = 0.f;

#define ALPHA_OF(kv, t4, out_a, okflag)                                        \
  {                                                                            \
    float s = qx * bf2f((kv)[0]) + __half2float(*(__half*)&(t4).x) * px;       \
    s += qy * bf2f((kv)[1]) + __half2float(*(__half*)&(t4).y) * py;            \
    s += qz * bf2f((kv)[2]) + __half2float(*(__half*)&(t4).z) * pz;            \
    s += qw * bf2f((kv)[3]) + __half2float(*(__half*)&(t4).w) * pw;            \
    s += __shfl_xor(s, 1);                                                     \
    s += __shfl_xor(s, 2);                                                     \
    s += __shfl_xor(s, 4);                                                     \
    s += __shfl_xor(s, 8);                                                     \
    out_a = (okflag) ? (s + qb) * 0.125f : 0.f;                                \
  }

#define STATE_UPDATE(a, kv, okflag)                                            \
  {                                                                            \
    float ea;                                                                  \
    if ((a) > m) {                                                             \
      float sc = __expf(m - (a));                                              \
      denom *= sc;                                                             \
      acc0 *= sc; acc1 *= sc; acc2 *= sc; acc3 *= sc;                          \
      m = (a);                                                                 \
      ea = 1.0f;                                                               \
    } else {                                                                   \
      ea = __expf((a) - m);                                                    \
    }                                                                          \
    denom += ea;                                                               \
    if (okflag) {                                                              \
      acc0 += ea * bf2f((kv)[4]);                                              \
      acc1 += ea * bf2f((kv)[5]);                                              \
      acc2 += ea * bf2f((kv)[6]);                                              \
      acc3 += ea * bf2f((kv)[7]);                                              \
    }                                                                          \
  }

  int p = s0;
  for (; p + 3 < s1; p += 4) {
    int srcA = ssrc[p], srcB = ssrc[p + 1], srcC = ssrc[p + 2], srcD = ssrc[p + 3];
    bool okA = (unsigned)srcA < NN, okB = (unsigned)srcB < NN;
    bool okC = (unsigned)srcC < NN, okD = (unsigned)srcD < NN;
    if (!okA) srcA = 0;
    if (!okB) srcB = 0;
    if (!okC) srcC = 0;
    if (!okD) srcD = 0;
    u16x8 kvA = *(const u16x8*)(qkvp + (size_t)srcA * NB + kvoff);
    u16x8 kvB = *(const u16x8*)(qkvp + (size_t)srcB * NB + kvoff);
    u16x8 kvC = *(const u16x8*)(qkvp + (size_t)srcC * NB + kvoff);
    u16x8 kvD = *(const u16x8*)(qkvp + (size_t)srcD * NB + kvoff);
    ushort4 tA = *(const ushort4*)(te_s + (size_t)p * 64 + jb);
    ushort4 tB = *(const ushort4*)(te_s + (size_t)(p + 1) * 64 + jb);
    ushort4 tC = *(const ushort4*)(te_s + (size_t)(p + 2) * 64 + jb);
    ushort4 tD = *(const ushort4*)(te_s + (size_t)(p + 3) * 64 + jb);

    float aA, aB, aC, aD;
    ALPHA_OF(kvA, tA, aA, okA)
    ALPHA_OF(kvB, tB, aB, okB)
    ALPHA_OF(kvC, tC, aC, okC)
    ALPHA_OF(kvD, tD, aD, okD)
    STATE_UPDATE(aA, kvA, okA)
    STATE_UPDATE(aB, kvB, okB)
    STATE_UPDATE(aC, kvC, okC)
    STATE_UPDATE(aD, kvD, okD)
  }
  for (; p < s1; ++p) {
    int src = ssrc[p];
    bool ok = (unsigned)src < NN;
    if (!ok) src = 0;
    u16x8 kv = *(const u16x8*)(qkvp + (size_t)src * NB + kvoff);
    ushort4 t4 = *(const ushort4*)(te_s + (size_t)p * 64 + jb);
    float a;
    ALPHA_OF(kv, t4, a, ok)
    STATE_UPDATE(a, kv, ok)
  }
#undef ALPHA_OF
#undef STATE_UPDATE

  float inv = 1.f / (denom + 1e-16f);
  ushort4 r;
  r.x = f2bf(fmaxf(acc0 * inv, 0.f));
  r.y = f2bf(fmaxf(acc1 * inv, 0.f));
  r.z = f2bf(fmaxf(acc2 * inv, 0.f));
  r.w = f2bf(fmaxf(acc3 * inv, 0.f));
  *(ushort4*)(xout + (size_t)n * HC + c) = r;
  if (DOY) {
    float yv = bf2f(r.x) * ldf(wc, c + 0, fbf);
    yv += bf2f(r.y) * ldf(wc, c + 1, fbf);
    yv += bf2f(r.z) * ldf(wc, c + 2, fbf);
    yv += bf2f(r.w) * ldf(wc, c + 3, fbf);
    for (int off = 32; off; off >>= 1) yv += __shfl_xor(yv, off);
    if (lane == 0) ynode[n] = yv;
  }
}

// ---------------- out[e] = y[src] + y[dst] + bc ----------------
__global__ __launch_bounds__(256) void final2_kernel(
    const int* __restrict__ flags, const void* __restrict__ eidx,
    const float* __restrict__ y, const void* __restrict__ bc,
    void* __restrict__ out) {
  bool is64 = flags[0] != 0, fbf = flags[1] != 0;
  int e = blockIdx.x * 256 + threadIdx.x;
  if (e >= NE) return;
  int src = ldsrc(eidx, e, is64);
  int dst = lddst(eidx, e, is64);
  if ((unsigned)src >= NN) src = 0;
  if ((unsigned)dst >= NN) dst = 0;
  stout(out, e, y[src] + y[dst] + ldf(bc, 0, fbf), fbf);
}

extern "C" void kernel_launch(void* const* d_in, const int* in_sizes, int n_in,
                              void* d_out, int out_size, void* d_ws, size_t ws_size,
                              hipStream_t stream) {
  const void* eidx  = d_in[0];
  const void* rawt  = d_in[1];
  const void* noise = d_in[2];
  const void* nemb  = d_in[3];
  const void *wq1 = d_in[4],  *bq1 = d_in[5];
  const void *wk1 = d_in[6],  *bk1 = d_in[7];
  const void *wv1 = d_in[8],  *bv1 = d_in[9];
  const void *wt1 = d_in[10], *bt1 = d_in[11];
  const void *wq2 = d_in[12], *bq2 = d_in[13];
  const void *wk2 = d_in[14], *bk2 = d_in[15];
  const void *wv2 = d_in[16], *bv2 = d_in[17];
  const void *wt2 = d_in[18], *bt2 = d_in[19];
  const void *wcp = d_in[20], *bcp = d_in[21];

  char* ws = (char*)d_ws;
  size_t off = 0;
  auto alloc = [&](size_t bytes) -> void* {
    void* p = ws + off;
    off += (bytes + 255) & ~(size_t)255;
    return p;
  };
  int*   flags  = (int*)alloc(256);
  float* divt   = (float*)alloc(256);
  u16*   WtBig  = (u16*)alloc((size_t)NB * HC * 2);
  float* biasBig= (float*)alloc((size_t)NB * 4);
  u16*   qkvp   = (u16*)alloc((size_t)NN * NB * 2);
  u16*   x1     = (u16*)alloc((size_t)NN * HC * 2);
  u16*   x2     = (u16*)alloc((size_t)NN * HC * 2);
  float* ynode  = (float*)alloc((size_t)NN * 4);
  int* offsets  = (int*)alloc((size_t)(NN + 1) * 4);
  int* cursor   = (int*)alloc((size_t)NN * 4);
  int* bsum     = (int*)alloc(256 * 4);
  int* ssrc     = (int*)alloc((size_t)NE * 4);
  float* stt    = (float*)alloc((size_t)NE * 4);
  u16* te_s     = (u16*)alloc((size_t)NE * 64 * 2);
  size_t need = off;

  int gN = (NN + 255) / 256, gE = (NE + 255) / 256;
  int nb = (NN + 255) / 256;

  if (ws_size < 1024) {
    raw_sentinel_kernel<<<gE, 256, 0, stream>>>((u16*)d_out);
    return;
  }
  devinit_kernel<<<1, 64, 0, stream>>>(eidx, nemb, flags, divt);
  if (need > ws_size) {
    sentinel_kernel<<<gE, 256, 0, stream>>>(flags, d_out);
    return;
  }

  // CSR by dst (+ sorted src / time)
  zero_kernel<<<gN, 256, 0, stream>>>(cursor, NN);
  hist_kernel<<<gE, 256, 0, stream>>>(flags, eidx, cursor);
  scan1_kernel<<<nb, 256, 0, stream>>>(cursor, offsets, bsum, NN);
  scan2_kernel<<<1, 256, 0, stream>>>(bsum, offsets, nb, NN);
  scan3_kernel<<<nb, 256, 0, stream>>>(offsets, bsum, cursor, NN);
  fill_kernel<<<gE, 256, 0, stream>>>(flags, eidx, rawt, noise, cursor, ssrc, stt);

  int gTe = (NE * 32 + 255) / 256;
  te_kernel<<<gTe, 256, 0, stream>>>(stt, divt, te_s);

  dim3 ggemm((NN + 127) / 128, NB / 128);   // 157 x 8
  dim3 gt1(NIN / 64, 4, 3), gt2(HC / 64, 4, 3);
  int gNode = (NN + 3) / 4;

  // ---- Layer 1 (A = raw node_emb, K=128) ----
  transw3_kernel<<<gt1, 256, 0, stream>>>(flags, wq1, wk1, wv1, WtBig, NIN);
  wcombbias_kernel<<<260, 256, 0, stream>>>(flags, wt1, WtBig, WtBig + (size_t)768 * NIN,
                                            bq1, bk1, bv1, biasBig, NIN);
  gemm_mfma<false><<<ggemm, 256, 0, stream>>>(flags, nemb, WtBig, biasBig, qkvp, NN, NIN);
  aggfused_kernel<0><<<gNode, 256, 0, stream>>>(flags, ssrc, offsets, te_s, qkvp, bt1,
                                                x1, wcp, ynode);

  // ---- Layer 2 (A = bf16 x1, K=256) ----
  transw3_kernel<<<gt2, 256, 0, stream>>>(flags, wq2, wk2, wv2, WtBig, HC);
  wcombbias_kernel<<<260, 256, 0, stream>>>(flags, wt2, WtBig, WtBig + (size_t)768 * HC,
                                            bq2, bk2, bv2, biasBig, HC);
  gemm_mfma<true><<<ggemm, 256, 0, stream>>>(flags, x1, WtBig, biasBig, qkvp, NN, HC);
  aggfused_kernel<1><<<gNode, 256, 0, stream>>>(flags, ssrc, offsets, te_s, qkvp, bt2,
                                                x2, wcp, ynode);

  // Edge scorer epilogue
  final2_kernel<<<gE, 256, 0, stream>>>(flags, eidx, ynode, bcp, d_out);
}